// Round 1
// baseline (94.316 us; speedup 1.0000x reference)
//
#include <hip/hip_runtime.h>

typedef __attribute__((ext_vector_type(8))) short bf16x8;
typedef __attribute__((ext_vector_type(4))) float f32x4;

#define MFMA16(a,b,c) __builtin_amdgcn_mfma_f32_16x16x32_bf16((a),(b),(c),0,0,0)

static __device__ __forceinline__ short f2bf(float f) {
  union { float f; unsigned u; } v; v.f = f;
  unsigned r = (v.u + 0x7FFFu + ((v.u >> 16) & 1u)) >> 16;
  return (short)r;
}

// ---------------- Kernel A: projections q/k/v/gate ----------------
// grid (64, 4, 4): 64 M-tiles of 64 rows (B*S=4096), 4 N-tiles of 64 (C=256),
// z: 0=Q (scaled), 1=K, 2=V(transposed), 3=gate
__global__ __launch_bounds__(256) void proj_kernel(
    const float* __restrict__ q_x, const float* __restrict__ kv_x,
    const float* __restrict__ Wq, const float* __restrict__ Wk,
    const float* __restrict__ Wv, const float* __restrict__ Wg,
    const float* __restrict__ b_g, const float* __restrict__ gbias,
    short* __restrict__ Qb, short* __restrict__ Kb, short* __restrict__ VTb,
    float* __restrict__ gate)
{
  const int z = blockIdx.z;
  const int m0 = blockIdx.x * 64, n0 = blockIdx.y * 64;
  const int t = threadIdx.x;
  const int lane = t & 63, wave = t >> 6;
  const int lo = lane & 15, hi = lane >> 4;
  const int wm = wave >> 1, wn = wave & 1;
  const float* X = (z == 0 || z == 3) ? q_x : kv_x;
  const float* W = (z == 0) ? Wq : (z == 1) ? Wk : (z == 2) ? Wv : Wg;

  __shared__ short Xs[64][40];  // +8 pad
  __shared__ short Ws[64][40];

  f32x4 acc00 = {0.f,0.f,0.f,0.f};
  f32x4 acc01 = acc00, acc10 = acc00, acc11 = acc00;

  const int row = t >> 2, cg = (t & 3) << 3;
  const float* xp0 = X + (size_t)(m0 + row) * 256 + cg;
  const float* wp0 = W + (size_t)(n0 + row) * 256 + cg;

  for (int kk = 0; kk < 256; kk += 32) {
    float4 xa = *(const float4*)(xp0 + kk);
    float4 xb = *(const float4*)(xp0 + kk + 4);
    float4 wa = *(const float4*)(wp0 + kk);
    float4 wb = *(const float4*)(wp0 + kk + 4);
    bf16x8 xv, wv8;
    xv[0]=f2bf(xa.x); xv[1]=f2bf(xa.y); xv[2]=f2bf(xa.z); xv[3]=f2bf(xa.w);
    xv[4]=f2bf(xb.x); xv[5]=f2bf(xb.y); xv[6]=f2bf(xb.z); xv[7]=f2bf(xb.w);
    wv8[0]=f2bf(wa.x); wv8[1]=f2bf(wa.y); wv8[2]=f2bf(wa.z); wv8[3]=f2bf(wa.w);
    wv8[4]=f2bf(wb.x); wv8[5]=f2bf(wb.y); wv8[6]=f2bf(wb.z); wv8[7]=f2bf(wb.w);
    __syncthreads();   // prev-iter readers done before overwrite
    *(bf16x8*)&Xs[row][cg] = xv;
    *(bf16x8*)&Ws[row][cg] = wv8;
    __syncthreads();
    bf16x8 a0 = *(const bf16x8*)&Xs[wm*32 + lo][hi*8];
    bf16x8 a1 = *(const bf16x8*)&Xs[wm*32 + 16 + lo][hi*8];
    bf16x8 b0 = *(const bf16x8*)&Ws[wn*32 + lo][hi*8];
    bf16x8 b1 = *(const bf16x8*)&Ws[wn*32 + 16 + lo][hi*8];
    acc00 = MFMA16(a0, b0, acc00);
    acc01 = MFMA16(a0, b1, acc01);
    acc10 = MFMA16(a1, b0, acc10);
    acc11 = MFMA16(a1, b1, acc11);
  }

  f32x4 accs[2][2] = {{acc00, acc01}, {acc10, acc11}};
  #pragma unroll
  for (int i = 0; i < 2; ++i)
  #pragma unroll
  for (int j = 0; j < 2; ++j)
  #pragma unroll
  for (int r = 0; r < 4; ++r) {
    int rg = m0 + wm*32 + i*16 + hi*4 + r;   // global row in [0,4096)
    int c  = n0 + wn*32 + j*16 + lo;         // out feature [0,256)
    float val = accs[i][j][r];
    int bb = rg >> 11, ss = rg & 2047;
    int hh = c >> 5,  dd = c & 31;
    if (z == 0) {
      Qb[(((size_t)(bb*8 + hh))*2048 + ss)*32 + dd] = f2bf(val * 0.17677669529663687f);
    } else if (z == 1) {
      Kb[(((size_t)(bb*8 + hh))*2048 + ss)*32 + dd] = f2bf(val);
    } else if (z == 2) {
      VTb[(((size_t)(bb*8 + hh))*32 + dd)*2048 + ss] = f2bf(val);
    } else {
      float g = val + b_g[c] + gbias[c];
      gate[(size_t)rg*256 + c] = 1.f / (1.f + __expf(-g));
    }
  }
}

// ---------------- Kernel B: flash attention with additive bias ----------------
// grid (32, 16): 32 q-tiles of 64, 16 = B*H. 4 waves, each owns 16 q rows.
__global__ __launch_bounds__(256) void attn_kernel(
    const short* __restrict__ Qb, const short* __restrict__ Kb,
    const short* __restrict__ VTb, const float* __restrict__ bias,
    short* __restrict__ Oattn)
{
  const int qt = blockIdx.x, bh = blockIdx.y;
  const int t = threadIdx.x, lane = t & 63, wv = t >> 6;
  const int lo = lane & 15, hi = lane >> 4;
  const int q0 = qt*64 + wv*16;

  __shared__ short Plds[4][16][72];  // per-wave P buffer, padded stride 72
  short (*P)[72] = Plds[wv];

  const bf16x8 qf = *(const bf16x8*)(Qb + ((size_t)bh*2048 + q0 + lo)*32 + hi*8);

  float m[4], lsum[4];
  f32x4 oacc[2];
  #pragma unroll
  for (int r = 0; r < 4; ++r) { m[r] = -1e30f; lsum[r] = 0.f; }
  oacc[0] = f32x4{0.f,0.f,0.f,0.f};
  oacc[1] = f32x4{0.f,0.f,0.f,0.f};

  const float* bp0 = bias + ((size_t)bh*2048 + q0 + hi*4)*2048 + lo;
  const short* kb0 = Kb + ((size_t)bh*2048 + lo)*32 + hi*8;
  const short* vt0 = VTb + ((size_t)bh*32 + lo)*2048 + hi*8;
  const f32x4 zero = {0.f,0.f,0.f,0.f};

  for (int kk0 = 0; kk0 < 2048; kk0 += 64) {
    // scores: 4 col-frags of 16 (KB=64), K dim = D = 32 in one MFMA
    f32x4 s[4];
    #pragma unroll
    for (int f = 0; f < 4; ++f) {
      bf16x8 kf = *(const bf16x8*)(kb0 + (size_t)(kk0 + f*16)*32);
      s[f] = MFMA16(qf, kf, zero);
    }
    // bias: D-layout direct loads (16 lanes x 64B contiguous per inst)
    float bv[4][4];
    #pragma unroll
    for (int f = 0; f < 4; ++f)
      #pragma unroll
      for (int r = 0; r < 4; ++r)
        bv[f][r] = bp0[(size_t)r*2048 + kk0 + f*16];
    #pragma unroll
    for (int f = 0; f < 4; ++f)
      #pragma unroll
      for (int r = 0; r < 4; ++r)
        s[f][r] += bv[f][r];
    // online softmax: rowmax over 4 frags in-lane + 16-lane shuffle reduce
    #pragma unroll
    for (int r = 0; r < 4; ++r) {
      float pm = fmaxf(fmaxf(s[0][r], s[1][r]), fmaxf(s[2][r], s[3][r]));
      pm = fmaxf(pm, __shfl_xor(pm, 1));
      pm = fmaxf(pm, __shfl_xor(pm, 2));
      pm = fmaxf(pm, __shfl_xor(pm, 4));
      pm = fmaxf(pm, __shfl_xor(pm, 8));
      float mn = fmaxf(m[r], pm);
      float sc = __expf(m[r] - mn);
      m[r] = mn;
      lsum[r] *= sc;
      oacc[0][r] *= sc;
      oacc[1][r] *= sc;
    }
    #pragma unroll
    for (int f = 0; f < 4; ++f)
      #pragma unroll
      for (int r = 0; r < 4; ++r) {
        float p = __expf(s[f][r] - m[r]);
        lsum[r] += p;                         // per-lane partial; reduce at end
        P[hi*4 + r][lo + f*16] = f2bf(p);     // D-layout -> row-major LDS
      }
    // PV: o[16q x 32d] += P[16x64] * V[64x32], via P A-frags + VT B-frags
    #pragma unroll
    for (int tt = 0; tt < 2; ++tt) {
      bf16x8 pa = *(const bf16x8*)&P[lo][tt*32 + hi*8];
      #pragma unroll
      for (int df = 0; df < 2; ++df) {
        bf16x8 vf = *(const bf16x8*)(vt0 + (size_t)df*16*2048 + kk0 + tt*32);
        oacc[df] = MFMA16(pa, vf, oacc[df]);
      }
    }
  }

  const int bb = bh >> 3, hh = bh & 7;
  #pragma unroll
  for (int r = 0; r < 4; ++r) {
    float tot = lsum[r];
    tot += __shfl_xor(tot, 1);
    tot += __shfl_xor(tot, 2);
    tot += __shfl_xor(tot, 4);
    tot += __shfl_xor(tot, 8);
    float inv = 1.f / tot;
    int q = q0 + hi*4 + r;
    #pragma unroll
    for (int df = 0; df < 2; ++df)
      Oattn[((size_t)bb*2048 + q)*256 + hh*32 + df*16 + lo] = f2bf(oacc[df][r] * inv);
  }
}

// ---------------- Kernel C: out projection + gating ----------------
__global__ __launch_bounds__(256) void outproj_kernel(
    const short* __restrict__ Oattn, const float* __restrict__ Wout,
    const float* __restrict__ b_out, const float* __restrict__ gate,
    float* __restrict__ out)
{
  const int m0 = blockIdx.x * 64, n0 = blockIdx.y * 64;
  const int t = threadIdx.x, lane = t & 63, wave = t >> 6;
  const int lo = lane & 15, hi = lane >> 4;
  const int wm = wave >> 1, wn = wave & 1;

  __shared__ short Xs[64][40];
  __shared__ short Ws[64][40];
  f32x4 acc00 = {0.f,0.f,0.f,0.f};
  f32x4 acc01 = acc00, acc10 = acc00, acc11 = acc00;

  const int row = t >> 2, cg = (t & 3) << 3;
  const short* xp0 = Oattn + (size_t)(m0 + row)*256 + cg;
  const float* wp0 = Wout + (size_t)(n0 + row)*256 + cg;

  for (int kk = 0; kk < 256; kk += 32) {
    bf16x8 xv = *(const bf16x8*)(xp0 + kk);
    float4 wa = *(const float4*)(wp0 + kk);
    float4 wb = *(const float4*)(wp0 + kk + 4);
    bf16x8 wv8;
    wv8[0]=f2bf(wa.x); wv8[1]=f2bf(wa.y); wv8[2]=f2bf(wa.z); wv8[3]=f2bf(wa.w);
    wv8[4]=f2bf(wb.x); wv8[5]=f2bf(wb.y); wv8[6]=f2bf(wb.z); wv8[7]=f2bf(wb.w);
    __syncthreads();
    *(bf16x8*)&Xs[row][cg] = xv;
    *(bf16x8*)&Ws[row][cg] = wv8;
    __syncthreads();
    bf16x8 a0 = *(const bf16x8*)&Xs[wm*32 + lo][hi*8];
    bf16x8 a1 = *(const bf16x8*)&Xs[wm*32 + 16 + lo][hi*8];
    bf16x8 b0 = *(const bf16x8*)&Ws[wn*32 + lo][hi*8];
    bf16x8 b1 = *(const bf16x8*)&Ws[wn*32 + 16 + lo][hi*8];
    acc00 = MFMA16(a0, b0, acc00);
    acc01 = MFMA16(a0, b1, acc01);
    acc10 = MFMA16(a1, b0, acc10);
    acc11 = MFMA16(a1, b1, acc11);
  }

  f32x4 accs[2][2] = {{acc00, acc01}, {acc10, acc11}};
  #pragma unroll
  for (int i = 0; i < 2; ++i)
  #pragma unroll
  for (int j = 0; j < 2; ++j)
  #pragma unroll
  for (int r = 0; r < 4; ++r) {
    int rg = m0 + wm*32 + i*16 + hi*4 + r;
    int c  = n0 + wn*32 + j*16 + lo;
    float val = accs[i][j][r] + b_out[c];
    out[(size_t)rg*256 + c] = val * gate[(size_t)rg*256 + c];
  }
}

extern "C" void kernel_launch(void* const* d_in, const int* in_sizes, int n_in,
                              void* d_out, int out_size, void* d_ws, size_t ws_size,
                              hipStream_t stream) {
  const float* q_x   = (const float*)d_in[0];
  const float* kv_x  = (const float*)d_in[1];
  const float* bias  = (const float*)d_in[2];
  const float* Wq    = (const float*)d_in[3];
  const float* Wk    = (const float*)d_in[4];
  const float* Wv    = (const float*)d_in[5];
  const float* Wout  = (const float*)d_in[6];
  const float* b_out = (const float*)d_in[7];
  const float* Wg    = (const float*)d_in[8];
  const float* b_g   = (const float*)d_in[9];
  const float* gbias = (const float*)d_in[10];
  float* out = (float*)d_out;

  char* w = (char*)d_ws;
  short* Qb    = (short*)(w);                      // 2 MB bf16 [BH][S][D]
  short* Kb    = (short*)(w + (1u << 21));         // 2 MB bf16 [BH][S][D]
  short* VTb   = (short*)(w + (2u << 21));         // 2 MB bf16 [BH][D][S]
  short* Oattn = (short*)(w + (3u << 21));         // 2 MB bf16 [B][S][C]
  float* gate  = (float*)(w + (4u << 21));         // 4 MB f32  [B][S][C]

  proj_kernel<<<dim3(64, 4, 4), 256, 0, stream>>>(
      q_x, kv_x, Wq, Wk, Wv, Wg, b_g, gbias, Qb, Kb, VTb, gate);
  attn_kernel<<<dim3(32, 16), 256, 0, stream>>>(Qb, Kb, VTb, bias, Oattn);
  outproj_kernel<<<dim3(64, 4), 256, 0, stream>>>(Oattn, Wout, b_out, gate, out);
}